// Round 10
// baseline (443.565 us; speedup 1.0000x reference)
//
#include <hip/hip_runtime.h>
#include <stdint.h>

#define NB 4
#define LD 4096
#define SD 4096
#define CD 256

static constexpr long CHUNK = (long)NB * LD * SD;     // elements per [N,L,S] output
static constexpr float SCALE = 0.0625f;               // 1/sqrt(256)
static constexpr float INV_TC = 1.0f / 25.6f;         // 1/(0.1*256)
static constexpr float THRV = 0.2f;

typedef __attribute__((ext_vector_type(8))) short bf16x8;
typedef __attribute__((ext_vector_type(4))) float f32x4;

__device__ __forceinline__ unsigned short f2bf(float x) {
  unsigned int u = __float_as_uint(x);
  return (unsigned short)((u + 0x7FFFu + ((u >> 16) & 1u)) >> 16);
}

__device__ __forceinline__ void gload_lds16(const void* g, void* l) {
  __builtin_amdgcn_global_load_lds((const __attribute__((address_space(1))) void*)g,
                                   (__attribute__((address_space(3))) void*)l, 16, 0, 0);
}

// NT only for write-once-never-reread streams (conf*): keep them OUT of L2/L3
// so the sim intermediate stays resident between k_gemm and k_softmax.
__device__ __forceinline__ void nt_store4(f32x4 v, float* p) {
  __builtin_nontemporal_store(v, (f32x4*)p);
}

// ---------------- Kernel 1: scale -> bf16 copies + fp32 squared norms (into ws) -------
__global__ __launch_bounds__(256) void k_prep(const float* __restrict__ f0,
                                              const float* __restrict__ f1,
                                              unsigned short* __restrict__ abf,
                                              unsigned short* __restrict__ bbf,
                                              float* __restrict__ sq0,
                                              float* __restrict__ sq1) {
  int wid = threadIdx.x >> 6, lane = threadIdx.x & 63;
  long row = (long)blockIdx.x * 4 + wid;               // over N*(L+S) rows
  const long nl = (long)NB * LD;
  const float* src;
  unsigned short* dst;
  float* sqd;
  if (row < nl) {
    src = f0 + row * CD; dst = abf + row * CD; sqd = sq0 + row;
  } else {
    long r = row - nl;
    src = f1 + r * CD; dst = bbf + r * CD; sqd = sq1 + r;
  }
  f32x4 v = *reinterpret_cast<const f32x4*>(src + lane * 4);
  v *= SCALE;
  ushort4 o;
  o.x = f2bf(v[0]); o.y = f2bf(v[1]); o.z = f2bf(v[2]); o.w = f2bf(v[3]);
  reinterpret_cast<ushort4*>(dst)[lane] = o;
  float s = v[0] * v[0] + v[1] * v[1] + v[2] * v[2] + v[3] * v[3];
  #pragma unroll
  for (int m = 1; m < 64; m <<= 1) s += __shfl_xor(s, m);
  if (lane == 0) *sqd = s;
}

// ---------------- 8-wave GEMM core: 128x128 tile, BK=64, double-buffered LDS ----------
// 512 threads: each of 8 waves owns a 64x32 output sub-tile -> acc[4][2] (32 VGPR),
// keeping total VGPR <=128 so 2 blocks/CU = 16 waves/CU hide staging + epilogue latency.
__device__ __forceinline__ void stage_tile(const char* aB, const char* bB, char* lbuf,
                                           int kt, int srow, int scolb, int wid) {
  #pragma unroll
  for (int i = 0; i < 2; ++i) {
    int row = i * 64 + srow;                           // srow 0..63 (t>>3)
    int sc = scolb ^ ((row & 7) << 4);                 // pre-swizzle source col
    gload_lds16(aB + (long)row * (CD * 2) + kt * 128 + sc,
                lbuf + i * 8192 + (wid << 10));
    gload_lds16(bB + (long)row * (CD * 2) + kt * 128 + sc,
                lbuf + 16384 + i * 8192 + (wid << 10));
  }
}

__device__ __forceinline__ void gemm_core(const char* aB, const char* bB, char* lds,
                                          int t, f32x4 (&acc)[4][2]) {
  int wid = t >> 6, lane = t & 63;
  int srow = t >> 3;                                   // 0..63 staging row
  int scolb = (t & 7) << 4;                            // 0..112 staging byte col
  int wrb = (wid >> 2) << 6;                           // wave rows: 0 / 64
  int wcb = (wid & 3) << 5;                            // wave cols: 0/32/64/96
  int lrow = lane & 15;
  int kgrp = lane >> 4;

  #pragma unroll
  for (int m = 0; m < 4; ++m)
    #pragma unroll
    for (int n = 0; n < 2; ++n)
      acc[m][n] = (f32x4){0.f, 0.f, 0.f, 0.f};

  stage_tile(aB, bB, lds, 0, srow, scolb, wid);        // prologue: fill buf0
  __syncthreads();

  #pragma unroll
  for (int kt = 0; kt < 4; ++kt) {
    char* cur = lds + (kt & 1) * 32768;
    if (kt < 3)                                        // prefetch next step into buf^1
      stage_tile(aB, bB, lds + ((kt + 1) & 1) * 32768, kt + 1, srow, scolb, wid);
    #pragma unroll
    for (int ks = 0; ks < 2; ++ks) {
      int kb = ks * 64 + kgrp * 16;
      bf16x8 af[4], bfr[2];
      #pragma unroll
      for (int m = 0; m < 4; ++m) {
        int r = wrb + m * 16 + lrow;
        af[m] = *(const bf16x8*)(cur + r * 128 + (kb ^ ((r & 7) << 4)));
      }
      #pragma unroll
      for (int n = 0; n < 2; ++n) {
        int r = wcb + n * 16 + lrow;
        bfr[n] = *(const bf16x8*)(cur + 16384 + r * 128 + (kb ^ ((r & 7) << 4)));
      }
      #pragma unroll
      for (int m = 0; m < 4; ++m)
        #pragma unroll
        for (int n = 0; n < 2; ++n)
          acc[m][n] = __builtin_amdgcn_mfma_f32_16x16x32_bf16(af[m], bfr[n], acc[m][n], 0, 0, 0);
    }
    __syncthreads();                                   // one barrier per K-step
  }
}

// ---------------- Kernel 2: GEMM -> sim (LDS-coalesced, TEMPORAL store) + exp sums ----
__global__ __launch_bounds__(512, 4) void k_gemm(const unsigned short* __restrict__ abf,
                                                 const unsigned short* __restrict__ bbf,
                                                 const float* __restrict__ sq0,
                                                 const float* __restrict__ sq1,
                                                 float* __restrict__ simout,
                                                 float* __restrict__ rowsum,
                                                 float* __restrict__ colsum) {
  __shared__ char lds[67584];                          // dbuf 64KB; epilogue [128][132] f32
  int t = threadIdx.x;
  int wid = t >> 6, lane = t & 63;
  int wrb = (wid >> 2) << 6, wcb = (wid & 3) << 5;
  int lrow = lane & 15, kgrp = lane >> 4;

  // bijective XCD-chunked swizzle: 4096 blocks, 8 XCDs, 512 per XCD.
  int wg = blockIdx.x;
  int swz = (wg & 7) * 512 + (wg >> 3);
  int bz = swz >> 10;
  int rem = swz & 1023;
  long tileM = (long)(rem >> 5) * 128;
  long tileS = (long)(rem & 31) * 128;
  const char* aB = (const char*)(abf + ((long)bz * LD + tileM) * CD);
  const char* bB = (const char*)(bbf + ((long)bz * SD + tileS) * CD);

  f32x4 acc[4][2];
  gemm_core(aB, bB, lds, t, acc);

  long gcol0 = (long)bz * SD + tileS + wcb;
  float sq1v[2];
  #pragma unroll
  for (int n = 0; n < 2; ++n) sq1v[n] = sq1[gcol0 + n * 16 + lrow];

  float ce[2] = {0.f, 0.f};
  float* ltile = (float*)lds;                          // [128][132] padded full tile

  // gemm_core ended with __syncthreads -> safe to overlay ltile on the dbuf region
  #pragma unroll
  for (int m = 0; m < 4; ++m) {
    #pragma unroll
    for (int i = 0; i < 4; ++i) {
      int lr = m * 16 + kgrp * 4 + i;                  // C/D: row=(lane>>4)*4+reg
      long gl = tileM + wrb + lr;
      float s0 = sq0[(long)bz * LD + gl];
      int q = wrb + lr;                                // LDS row 0..127
      float rs = 0.f;
      #pragma unroll
      for (int n = 0; n < 2; ++n) {
        float inner = acc[m][n][i];
        float d2 = fmaxf(s0 + sq1v[n] - 2.0f * inner, 0.f);
        float sv = -__builtin_sqrtf(d2) * INV_TC;
        ltile[q * 132 + wcb + n * 16 + lrow] = sv;
        float e = __expf(sv);
        rs += e;
        ce[n] += e;
      }
      #pragma unroll
      for (int d = 1; d < 16; d <<= 1) rs += __shfl_xor(rs, d);
      if (lrow == 0) atomicAdd(&rowsum[(long)bz * LD + gl], rs);
    }
  }
  __syncthreads();
  // cooperative coalesced store: 128 rows x 128 cols, 512B contiguous per row.
  // TEMPORAL store: sim must allocate in L2/L3 so k_softmax's re-read hits cache.
  #pragma unroll
  for (int j = 0; j < 8; ++j) {
    int f = t + 512 * j;                               // 0..4095 float4 slots
    int r = f >> 5;                                    // LDS row 0..127
    int c4 = f & 31;                                   // float4 col 0..31
    long grow = tileM + r;
    f32x4 v = *(const f32x4*)&ltile[r * 132 + c4 * 4];
    *(f32x4*)(simout + ((long)bz * LD + grow) * SD + tileS + c4 * 4) = v;
  }

  #pragma unroll
  for (int n = 0; n < 2; ++n) {
    float cs = ce[n];
    cs += __shfl_xor(cs, 16);
    cs += __shfl_xor(cs, 32);
    if (kgrp == 0) atomicAdd(&colsum[gcol0 + n * 16 + lrow], cs);
  }
}

// ---------------- Kernel 3: dual softmax + packed row/col argmax (wave-owns-row) ------
__global__ __launch_bounds__(256) void k_softmax(const float* __restrict__ sim,
                                                 const float* __restrict__ rowsum,
                                                 const float* __restrict__ colsum,
                                                 float* __restrict__ conf,
                                                 float* __restrict__ conf0,
                                                 float* __restrict__ conf1,
                                                 unsigned long long* __restrict__ rowpack,
                                                 unsigned long long* __restrict__ colpack) {
  __shared__ unsigned long long rmx[64];
  __shared__ unsigned long long cmx[512];
  int t = threadIdx.x;
  int w = t >> 6, lane = t & 63;
  cmx[t] = 0ull;
  cmx[t + 256] = 0ull;
  __syncthreads();

  int n = blockIdx.z;
  long rbase = (long)blockIdx.y * 64;
  long cbase = (long)blockIdx.x * 512;

  // per-thread fixed column slots: it*256 + lane*4 + q
  float invc[2][4];
  unsigned long long cpk[2][4];
  #pragma unroll
  for (int it = 0; it < 2; ++it) {
    f32x4 cs = *(const f32x4*)(colsum + (long)n * SD + cbase + it * 256 + lane * 4);
    invc[it][0] = 1.0f / cs[0]; invc[it][1] = 1.0f / cs[1];
    invc[it][2] = 1.0f / cs[2]; invc[it][3] = 1.0f / cs[3];
    cpk[it][0] = cpk[it][1] = cpk[it][2] = cpk[it][3] = 0ull;
  }

  #pragma unroll 2
  for (int j = 0; j < 16; ++j) {
    int r = w + j * 4;                                 // wave-uniform row, unique owner
    long gr = rbase + r;
    float invr = 1.0f / rowsum[(long)n * LD + gr];
    long rowoff = ((long)n * LD + gr) * SD + cbase;
    unsigned long long rbest = 0ull;
    #pragma unroll
    for (int it = 0; it < 2; ++it) {
      long idx = rowoff + it * 256 + lane * 4;
      f32x4 sv = *(const f32x4*)(sim + idx);           // TEMPORAL: hit L3-resident sim
      f32x4 cf, c0v, c1v;
      #pragma unroll
      for (int q = 0; q < 4; ++q) {
        float e = __expf(sv[q]);
        float a0 = e * invc[it][q];                    // softmax over L (axis=1)
        float a1 = e * invr;                           // softmax over S (axis=2)
        float c = a0 * a1;
        c0v[q] = a0;
        c1v[q] = a1;
        cf[q] = c;
        unsigned long long pk = ((unsigned long long)__float_as_uint(c) << 32) |
                                (unsigned int)(~(unsigned int)(cbase + it * 256 + lane * 4 + q));
        rbest = pk > rbest ? pk : rbest;
        cpk[it][q] = pk > cpk[it][q] ? pk : cpk[it][q];
      }
      nt_store4(cf, conf + idx);                       // NT: never re-read, don't evict sim
      nt_store4(c0v, conf0 + idx);
      nt_store4(c1v, conf1 + idx);
    }
    #pragma unroll
    for (int d = 1; d < 64; d <<= 1) {                 // one reduce per row (not per tile)
      unsigned long long o = __shfl_xor(rbest, d);
      rbest = o > rbest ? o : rbest;
    }
    if (lane == 0) rmx[r] = rbest;                     // unique writer -> plain store
  }
  #pragma unroll
  for (int it = 0; it < 2; ++it)
    #pragma unroll
    for (int q = 0; q < 4; ++q)
      atomicMax(&cmx[it * 256 + lane * 4 + q], cpk[it][q]);
  __syncthreads();
  if (t < 64) atomicMax(&rowpack[(long)n * LD + rbase + t], rmx[t]);
  atomicMax(&colpack[(long)n * SD + cbase + t], cmx[t]);
  atomicMax(&colpack[(long)n * SD + cbase + 256 + t], cmx[t + 256]);
}

// ---------------- Kernel 4: finalize mutual-NN match outputs --------------------------
__global__ __launch_bounds__(256) void k_final(const unsigned long long* __restrict__ rowpack,
                                               const unsigned long long* __restrict__ colpack,
                                               float* __restrict__ maskv,
                                               float* __restrict__ jids,
                                               float* __restrict__ mconf) {
  long idx = (long)blockIdx.x * 256 + threadIdx.x;
  if (idx >= (long)NB * LD) return;
  int n = (int)(idx / LD);
  unsigned long long rp = rowpack[idx];
  unsigned int cbits = (unsigned int)(rp >> 32);
  float cval = __uint_as_float(cbits);
  unsigned int col = ~(unsigned int)rp;
  bool valid = (cval > THRV) && (col < (unsigned int)SD);
  if (valid) {
    unsigned long long cp = colpack[(long)n * SD + col];
    valid = ((unsigned int)(cp >> 32)) == cbits;       // conf == colmax
  }
  maskv[idx] = valid ? 1.0f : 0.0f;
  jids[idx]  = valid ? (float)col : 0.0f;
  mconf[idx] = valid ? cval : 0.0f;
}

extern "C" void kernel_launch(void* const* d_in, const int* in_sizes, int n_in,
                              void* d_out, int out_size, void* d_ws, size_t ws_size,
                              hipStream_t stream) {
  const float* f0 = (const float*)d_in[0];
  const float* f1 = (const float*)d_in[1];
  float* out = (float*)d_out;
  float* conf  = out;                  // chunk 0
  float* conf0 = out + CHUNK;          // chunk 1
  float* conf1 = out + 2 * CHUNK;      // chunk 2
  float* simo  = out + 3 * CHUNK;      // chunk 3
  float* maskv = out + 4 * CHUNK;      // [N,L]
  float* jids  = maskv + (long)NB * LD;
  float* mconf = jids + (long)NB * LD;

  char* ws = (char*)d_ws;
  unsigned short* abf = (unsigned short*)ws;                         // 8 MiB
  unsigned short* bbf = (unsigned short*)(ws + 8388608);             // 8 MiB
  float* sq0 = (float*)(ws + 16777216);                              // 64 KiB
  float* sq1 = (float*)(ws + 16777216 + 65536);                      // 64 KiB
  char* accums = ws + 16908288;
  float* rowsum = (float*)accums;                                    // 64 KiB
  float* colsum = (float*)(accums + 65536);                          // 64 KiB
  unsigned long long* rowpack = (unsigned long long*)(accums + 131072);   // 128 KiB
  unsigned long long* colpack = (unsigned long long*)(accums + 262144);   // 128 KiB
  (void)hipMemsetAsync(accums, 0, 393216, stream);

  k_prep<<<dim3((NB * (LD + SD)) / 4), dim3(256), 0, stream>>>(f0, f1, abf, bbf, sq0, sq1);
  k_gemm<<<dim3(4096), dim3(512), 0, stream>>>(abf, bbf, sq0, sq1, simo, rowsum, colsum);
  k_softmax<<<dim3(SD / 512, LD / 64, NB), dim3(256), 0, stream>>>(simo, rowsum, colsum,
                                                                   conf, conf0, conf1,
                                                                   rowpack, colpack);
  k_final<<<dim3((NB * LD + 255) / 256), dim3(256), 0, stream>>>(rowpack, colpack,
                                                                 maskv, jids, mconf);
}

// Round 11
// 346.264 us; speedup vs baseline: 1.2810x; 1.2810x over previous
//
#include <hip/hip_runtime.h>
#include <stdint.h>

#define NB 4
#define LD 4096
#define SD 4096
#define CD 256

static constexpr long CHUNK = (long)NB * LD * SD;     // elements per [N,L,S] output
static constexpr float SCALE = 0.0625f;               // 1/sqrt(256)
static constexpr float INV_TC = 1.0f / 25.6f;         // 1/(0.1*256)
static constexpr float THRV = 0.2f;

typedef __attribute__((ext_vector_type(8))) short bf16x8;
typedef __attribute__((ext_vector_type(4))) float f32x4;

__device__ __forceinline__ unsigned short f2bf(float x) {
  unsigned int u = __float_as_uint(x);
  return (unsigned short)((u + 0x7FFFu + ((u >> 16) & 1u)) >> 16);
}

__device__ __forceinline__ void gload_lds16(const void* g, void* l) {
  __builtin_amdgcn_global_load_lds((const __attribute__((address_space(1))) void*)g,
                                   (__attribute__((address_space(3))) void*)l, 16, 0, 0);
}

// NT only for write-once-never-reread streams (conf*): keep them OUT of L2/L3
// so the sim intermediate stays resident between k_gemm and k_softmax.
__device__ __forceinline__ void nt_store4(f32x4 v, float* p) {
  __builtin_nontemporal_store(v, (f32x4*)p);
}

// ---------------- Kernel 1: scale -> bf16 copies + fp32 squared norms (into ws) -------
__global__ __launch_bounds__(256) void k_prep(const float* __restrict__ f0,
                                              const float* __restrict__ f1,
                                              unsigned short* __restrict__ abf,
                                              unsigned short* __restrict__ bbf,
                                              float* __restrict__ sq0,
                                              float* __restrict__ sq1) {
  int wid = threadIdx.x >> 6, lane = threadIdx.x & 63;
  long row = (long)blockIdx.x * 4 + wid;               // over N*(L+S) rows
  const long nl = (long)NB * LD;
  const float* src;
  unsigned short* dst;
  float* sqd;
  if (row < nl) {
    src = f0 + row * CD; dst = abf + row * CD; sqd = sq0 + row;
  } else {
    long r = row - nl;
    src = f1 + r * CD; dst = bbf + r * CD; sqd = sq1 + r;
  }
  f32x4 v = *reinterpret_cast<const f32x4*>(src + lane * 4);
  v *= SCALE;
  ushort4 o;
  o.x = f2bf(v[0]); o.y = f2bf(v[1]); o.z = f2bf(v[2]); o.w = f2bf(v[3]);
  reinterpret_cast<ushort4*>(dst)[lane] = o;
  float s = v[0] * v[0] + v[1] * v[1] + v[2] * v[2] + v[3] * v[3];
  #pragma unroll
  for (int m = 1; m < 64; m <<= 1) s += __shfl_xor(s, m);
  if (lane == 0) *sqd = s;
}

// ---------------- GEMM core: 128x128 tile, BK=32, double-buffered LDS (33 KB) ---------
// BK=32 halves the dbuf footprint vs BK=64 (16.5 KB/buffer) -> 4 blocks/CU while
// keeping the prefetch-before-compute schedule. ks-plane layout (plane stride 2064 =
// 128*16 + 16 pad): wave-uniform plane per staging wave satisfies global_load_lds's
// linear-dest rule with NO swizzle; fragment reads spread evenly over all 32 banks.
__device__ __forceinline__ void stage32(const char* aB, const char* bB, char* lbuf,
                                        int kt, int t) {
  #pragma unroll
  for (int i = 0; i < 2; ++i) {
    int s = t + i * 256;                               // slot 0..511
    int ks = s >> 7;                                   // k-plane 0..3 (wave-uniform)
    int r = s & 127;                                   // row 0..127
    long goff = (long)r * (CD * 2) + kt * 64 + ks * 16;
    int loff = ks * 2064 + r * 16;                     // = uniform base + lane*16
    gload_lds16(aB + goff, lbuf + loff);
    gload_lds16(bB + goff, lbuf + 8256 + loff);
  }
}

__device__ __forceinline__ void gemm_core(const char* aB, const char* bB, char* lds,
                                          int t, f32x4 (&acc)[4][4]) {
  int wid = t >> 6, lane = t & 63;
  int wrb = (wid >> 1) << 6;
  int wcb = (wid & 1) << 6;
  int lrow = lane & 15;
  int kgrp = lane >> 4;

  #pragma unroll
  for (int m = 0; m < 4; ++m)
    #pragma unroll
    for (int n = 0; n < 4; ++n)
      acc[m][n] = (f32x4){0.f, 0.f, 0.f, 0.f};

  stage32(aB, bB, lds, 0, t);                          // prologue: fill buf0
  __syncthreads();

  #pragma unroll
  for (int kt = 0; kt < 8; ++kt) {                     // K-chunk order == R7 (kt x ks)
    char* cur = lds + (kt & 1) * 16512;
    if (kt < 7)                                        // prefetch next step into buf^1
      stage32(aB, bB, lds + ((kt + 1) & 1) * 16512, kt + 1, t);
    int kbp = kgrp * 2064;                             // this lane's k-plane
    bf16x8 af[4], bfr[4];
    #pragma unroll
    for (int m = 0; m < 4; ++m)
      af[m] = *(const bf16x8*)(cur + kbp + (wrb + m * 16 + lrow) * 16);
    #pragma unroll
    for (int n = 0; n < 4; ++n)
      bfr[n] = *(const bf16x8*)(cur + 8256 + kbp + (wcb + n * 16 + lrow) * 16);
    #pragma unroll
    for (int m = 0; m < 4; ++m)
      #pragma unroll
      for (int n = 0; n < 4; ++n)
        acc[m][n] = __builtin_amdgcn_mfma_f32_16x16x32_bf16(af[m], bfr[n], acc[m][n], 0, 0, 0);
    __syncthreads();                                   // one barrier per K-step
  }
}

// ---------------- Kernel 2: GEMM -> sim (LDS-coalesced, TEMPORAL store) + exp sums ----
__global__ __launch_bounds__(256, 4) void k_gemm(const unsigned short* __restrict__ abf,
                                                 const unsigned short* __restrict__ bbf,
                                                 const float* __restrict__ sq0,
                                                 const float* __restrict__ sq1,
                                                 float* __restrict__ simout,
                                                 float* __restrict__ rowsum,
                                                 float* __restrict__ colsum) {
  __shared__ char lds[33792];                          // dbuf 2x16.5KB; epilogue [64][132]
  int t = threadIdx.x;
  int wid = t >> 6, lane = t & 63;
  int wrb = (wid >> 1) << 6, wcb = (wid & 1) << 6;
  int lrow = lane & 15, kgrp = lane >> 4;

  // bijective XCD-chunked swizzle: 4096 blocks, 8 XCDs, 512 per XCD.
  int wg = blockIdx.x;
  int swz = (wg & 7) * 512 + (wg >> 3);
  int bz = swz >> 10;
  int rem = swz & 1023;
  long tileM = (long)(rem >> 5) * 128;
  long tileS = (long)(rem & 31) * 128;
  const char* aB = (const char*)(abf + ((long)bz * LD + tileM) * CD);
  const char* bB = (const char*)(bbf + ((long)bz * SD + tileS) * CD);

  f32x4 acc[4][4];
  gemm_core(aB, bB, lds, t, acc);

  long gcol0 = (long)bz * SD + tileS + wcb;
  float sq1v[4];
  #pragma unroll
  for (int n = 0; n < 4; ++n) sq1v[n] = sq1[gcol0 + n * 16 + lrow];

  float ce[4] = {0.f, 0.f, 0.f, 0.f};
  float* ltile = (float*)lds;                          // [64][132] padded half-tile

  #pragma unroll
  for (int h = 0; h < 2; ++h) {                        // two 64-row halves
    __syncthreads();                                   // LDS reuse guard
    #pragma unroll
    for (int mm = 0; mm < 2; ++mm) {
      int m = 2 * h + mm;
      #pragma unroll
      for (int i = 0; i < 4; ++i) {
        int lr = m * 16 + kgrp * 4 + i;                // C/D: row=(lane>>4)*4+reg
        long gl = tileM + wrb + lr;
        float s0 = sq0[(long)bz * LD + gl];
        int q = (wid >> 1) * 32 + mm * 16 + kgrp * 4 + i;  // LDS row 0..63
        float rs = 0.f;
        #pragma unroll
        for (int n = 0; n < 4; ++n) {
          float inner = acc[m][n][i];
          float d2 = fmaxf(s0 + sq1v[n] - 2.0f * inner, 0.f);
          float sv = -__builtin_sqrtf(d2) * INV_TC;
          ltile[q * 132 + wcb + n * 16 + lrow] = sv;
          float e = __expf(sv);
          rs += e;
          ce[n] += e;
        }
        #pragma unroll
        for (int d = 1; d < 16; d <<= 1) rs += __shfl_xor(rs, d);
        if (lrow == 0) atomicAdd(&rowsum[(long)bz * LD + gl], rs);
      }
    }
    __syncthreads();
    // cooperative coalesced store: 64 rows x 128 cols, 512B contiguous per row.
    // TEMPORAL store: sim must allocate in L2/L3 so k_softmax's re-read hits cache.
    #pragma unroll
    for (int j = 0; j < 8; ++j) {
      int f = t + 256 * j;                             // 0..2047 float4 slots
      int r = f >> 5;                                  // LDS row 0..63
      int c4 = f & 31;                                 // float4 col 0..31
      long grow = tileM + (r >> 5) * 64 + 32 * h + (r & 31);
      f32x4 v = *(const f32x4*)&ltile[r * 132 + c4 * 4];
      *(f32x4*)(simout + ((long)bz * LD + grow) * SD + tileS + c4 * 4) = v;
    }
  }

  #pragma unroll
  for (int n = 0; n < 4; ++n) {
    float cs = ce[n];
    cs += __shfl_xor(cs, 16);
    cs += __shfl_xor(cs, 32);
    if (kgrp == 0) atomicAdd(&colsum[gcol0 + n * 16 + lrow], cs);
  }
}

// ---------------- Kernel 3: dual softmax + packed row/col argmax (wave-owns-row) ------
__global__ __launch_bounds__(256) void k_softmax(const float* __restrict__ sim,
                                                 const float* __restrict__ rowsum,
                                                 const float* __restrict__ colsum,
                                                 float* __restrict__ conf,
                                                 float* __restrict__ conf0,
                                                 float* __restrict__ conf1,
                                                 unsigned long long* __restrict__ rowpack,
                                                 unsigned long long* __restrict__ colpack) {
  __shared__ unsigned long long rmx[64];
  __shared__ unsigned long long cmx[512];
  int t = threadIdx.x;
  int w = t >> 6, lane = t & 63;
  cmx[t] = 0ull;
  cmx[t + 256] = 0ull;
  __syncthreads();

  int n = blockIdx.z;
  long rbase = (long)blockIdx.y * 64;
  long cbase = (long)blockIdx.x * 512;

  // per-thread fixed column slots: it*256 + lane*4 + q
  float invc[2][4];
  unsigned long long cpk[2][4];
  #pragma unroll
  for (int it = 0; it < 2; ++it) {
    f32x4 cs = *(const f32x4*)(colsum + (long)n * SD + cbase + it * 256 + lane * 4);
    invc[it][0] = 1.0f / cs[0]; invc[it][1] = 1.0f / cs[1];
    invc[it][2] = 1.0f / cs[2]; invc[it][3] = 1.0f / cs[3];
    cpk[it][0] = cpk[it][1] = cpk[it][2] = cpk[it][3] = 0ull;
  }

  #pragma unroll 2
  for (int j = 0; j < 16; ++j) {
    int r = w + j * 4;                                 // wave-uniform row, unique owner
    long gr = rbase + r;
    float invr = 1.0f / rowsum[(long)n * LD + gr];
    long rowoff = ((long)n * LD + gr) * SD + cbase;
    unsigned long long rbest = 0ull;
    #pragma unroll
    for (int it = 0; it < 2; ++it) {
      long idx = rowoff + it * 256 + lane * 4;
      f32x4 sv = *(const f32x4*)(sim + idx);           // TEMPORAL: hit L3-resident sim
      f32x4 cf, c0v, c1v;
      #pragma unroll
      for (int q = 0; q < 4; ++q) {
        float e = __expf(sv[q]);
        float a0 = e * invc[it][q];                    // softmax over L (axis=1)
        float a1 = e * invr;                           // softmax over S (axis=2)
        float c = a0 * a1;
        c0v[q] = a0;
        c1v[q] = a1;
        cf[q] = c;
        unsigned long long pk = ((unsigned long long)__float_as_uint(c) << 32) |
                                (unsigned int)(~(unsigned int)(cbase + it * 256 + lane * 4 + q));
        rbest = pk > rbest ? pk : rbest;
        cpk[it][q] = pk > cpk[it][q] ? pk : cpk[it][q];
      }
      nt_store4(cf, conf + idx);                       // NT: never re-read, don't evict sim
      nt_store4(c0v, conf0 + idx);
      nt_store4(c1v, conf1 + idx);
    }
    #pragma unroll
    for (int d = 1; d < 64; d <<= 1) {                 // one reduce per row (not per tile)
      unsigned long long o = __shfl_xor(rbest, d);
      rbest = o > rbest ? o : rbest;
    }
    if (lane == 0) rmx[r] = rbest;                     // unique writer -> plain store
  }
  #pragma unroll
  for (int it = 0; it < 2; ++it)
    #pragma unroll
    for (int q = 0; q < 4; ++q)
      atomicMax(&cmx[it * 256 + lane * 4 + q], cpk[it][q]);
  __syncthreads();
  if (t < 64) atomicMax(&rowpack[(long)n * LD + rbase + t], rmx[t]);
  atomicMax(&colpack[(long)n * SD + cbase + t], cmx[t]);
  atomicMax(&colpack[(long)n * SD + cbase + 256 + t], cmx[t + 256]);
}

// ---------------- Kernel 4: finalize mutual-NN match outputs --------------------------
__global__ __launch_bounds__(256) void k_final(const unsigned long long* __restrict__ rowpack,
                                               const unsigned long long* __restrict__ colpack,
                                               float* __restrict__ maskv,
                                               float* __restrict__ jids,
                                               float* __restrict__ mconf) {
  long idx = (long)blockIdx.x * 256 + threadIdx.x;
  if (idx >= (long)NB * LD) return;
  int n = (int)(idx / LD);
  unsigned long long rp = rowpack[idx];
  unsigned int cbits = (unsigned int)(rp >> 32);
  float cval = __uint_as_float(cbits);
  unsigned int col = ~(unsigned int)rp;
  bool valid = (cval > THRV) && (col < (unsigned int)SD);
  if (valid) {
    unsigned long long cp = colpack[(long)n * SD + col];
    valid = ((unsigned int)(cp >> 32)) == cbits;       // conf == colmax
  }
  maskv[idx] = valid ? 1.0f : 0.0f;
  jids[idx]  = valid ? (float)col : 0.0f;
  mconf[idx] = valid ? cval : 0.0f;
}

extern "C" void kernel_launch(void* const* d_in, const int* in_sizes, int n_in,
                              void* d_out, int out_size, void* d_ws, size_t ws_size,
                              hipStream_t stream) {
  const float* f0 = (const float*)d_in[0];
  const float* f1 = (const float*)d_in[1];
  float* out = (float*)d_out;
  float* conf  = out;                  // chunk 0
  float* conf0 = out + CHUNK;          // chunk 1
  float* conf1 = out + 2 * CHUNK;      // chunk 2
  float* simo  = out + 3 * CHUNK;      // chunk 3
  float* maskv = out + 4 * CHUNK;      // [N,L]
  float* jids  = maskv + (long)NB * LD;
  float* mconf = jids + (long)NB * LD;

  char* ws = (char*)d_ws;
  unsigned short* abf = (unsigned short*)ws;                         // 8 MiB
  unsigned short* bbf = (unsigned short*)(ws + 8388608);             // 8 MiB
  float* sq0 = (float*)(ws + 16777216);                              // 64 KiB
  float* sq1 = (float*)(ws + 16777216 + 65536);                      // 64 KiB
  char* accums = ws + 16908288;
  float* rowsum = (float*)accums;                                    // 64 KiB
  float* colsum = (float*)(accums + 65536);                          // 64 KiB
  unsigned long long* rowpack = (unsigned long long*)(accums + 131072);   // 128 KiB
  unsigned long long* colpack = (unsigned long long*)(accums + 262144);   // 128 KiB
  (void)hipMemsetAsync(accums, 0, 393216, stream);

  k_prep<<<dim3((NB * (LD + SD)) / 4), dim3(256), 0, stream>>>(f0, f1, abf, bbf, sq0, sq1);
  k_gemm<<<dim3(4096), dim3(256), 0, stream>>>(abf, bbf, sq0, sq1, simo, rowsum, colsum);
  k_softmax<<<dim3(SD / 512, LD / 64, NB), dim3(256), 0, stream>>>(simo, rowsum, colsum,
                                                                   conf, conf0, conf1,
                                                                   rowpack, colpack);
  k_final<<<dim3((NB * LD + 255) / 256), dim3(256), 0, stream>>>(rowpack, colpack,
                                                                 maskv, jids, mconf);
}

// Round 12
// 343.126 us; speedup vs baseline: 1.2927x; 1.0091x over previous
//
#include <hip/hip_runtime.h>
#include <stdint.h>

#define NB 4
#define LD 4096
#define SD 4096
#define CD 256

static constexpr long CHUNK = (long)NB * LD * SD;     // elements per [N,L,S] output
static constexpr float SCALE = 0.0625f;               // 1/sqrt(256)
static constexpr float INV_TC = 1.0f / 25.6f;         // 1/(0.1*256)
static constexpr float THRV = 0.2f;

typedef __attribute__((ext_vector_type(8))) short bf16x8;
typedef __attribute__((ext_vector_type(4))) float f32x4;

__device__ __forceinline__ unsigned short f2bf(float x) {
  unsigned int u = __float_as_uint(x);
  return (unsigned short)((u + 0x7FFFu + ((u >> 16) & 1u)) >> 16);
}

__device__ __forceinline__ void gload_lds16(const void* g, void* l) {
  __builtin_amdgcn_global_load_lds((const __attribute__((address_space(1))) void*)g,
                                   (__attribute__((address_space(3))) void*)l, 16, 0, 0);
}

// NT only for write-once-never-reread streams (conf*): keep them OUT of L2/L3
// so the sim intermediate stays resident between k_gemm and k_softmax.
__device__ __forceinline__ void nt_store4(f32x4 v, float* p) {
  __builtin_nontemporal_store(v, (f32x4*)p);
}

// ---------------- Kernel 1: scale -> bf16 copies + fp32 squared norms (into ws) -------
__global__ __launch_bounds__(256) void k_prep(const float* __restrict__ f0,
                                              const float* __restrict__ f1,
                                              unsigned short* __restrict__ abf,
                                              unsigned short* __restrict__ bbf,
                                              float* __restrict__ sq0,
                                              float* __restrict__ sq1) {
  int wid = threadIdx.x >> 6, lane = threadIdx.x & 63;
  long row = (long)blockIdx.x * 4 + wid;               // over N*(L+S) rows
  const long nl = (long)NB * LD;
  const float* src;
  unsigned short* dst;
  float* sqd;
  if (row < nl) {
    src = f0 + row * CD; dst = abf + row * CD; sqd = sq0 + row;
  } else {
    long r = row - nl;
    src = f1 + r * CD; dst = bbf + r * CD; sqd = sq1 + r;
  }
  f32x4 v = *reinterpret_cast<const f32x4*>(src + lane * 4);
  v *= SCALE;
  ushort4 o;
  o.x = f2bf(v[0]); o.y = f2bf(v[1]); o.z = f2bf(v[2]); o.w = f2bf(v[3]);
  reinterpret_cast<ushort4*>(dst)[lane] = o;
  float s = v[0] * v[0] + v[1] * v[1] + v[2] * v[2] + v[3] * v[3];
  #pragma unroll
  for (int m = 1; m < 64; m <<= 1) s += __shfl_xor(s, m);
  if (lane == 0) *sqd = s;
}

// ---------------- GEMM core: 128x128 tile, BK=32, double-buffered LDS (33 KB) ---------
__device__ __forceinline__ void stage32(const char* aB, const char* bB, char* lbuf,
                                        int kt, int t) {
  #pragma unroll
  for (int i = 0; i < 2; ++i) {
    int s = t + i * 256;                               // slot 0..511
    int ks = s >> 7;                                   // k-plane 0..3 (wave-uniform)
    int r = s & 127;                                   // row 0..127
    long goff = (long)r * (CD * 2) + kt * 64 + ks * 16;
    int loff = ks * 2064 + r * 16;                     // = uniform base + lane*16
    gload_lds16(aB + goff, lbuf + loff);
    gload_lds16(bB + goff, lbuf + 8256 + loff);
  }
}

__device__ __forceinline__ void gemm_core(const char* aB, const char* bB, char* lds,
                                          int t, f32x4 (&acc)[4][4]) {
  int wid = t >> 6, lane = t & 63;
  int wrb = (wid >> 1) << 6;
  int wcb = (wid & 1) << 6;
  int lrow = lane & 15;
  int kgrp = lane >> 4;

  #pragma unroll
  for (int m = 0; m < 4; ++m)
    #pragma unroll
    for (int n = 0; n < 4; ++n)
      acc[m][n] = (f32x4){0.f, 0.f, 0.f, 0.f};

  stage32(aB, bB, lds, 0, t);                          // prologue: fill buf0
  __syncthreads();

  #pragma unroll
  for (int kt = 0; kt < 8; ++kt) {                     // K-chunk order == R7 (kt x ks)
    char* cur = lds + (kt & 1) * 16512;
    if (kt < 7)                                        // prefetch next step into buf^1
      stage32(aB, bB, lds + ((kt + 1) & 1) * 16512, kt + 1, t);
    int kbp = kgrp * 2064;                             // this lane's k-plane
    bf16x8 af[4], bfr[4];
    #pragma unroll
    for (int m = 0; m < 4; ++m)
      af[m] = *(const bf16x8*)(cur + kbp + (wrb + m * 16 + lrow) * 16);
    #pragma unroll
    for (int n = 0; n < 4; ++n)
      bfr[n] = *(const bf16x8*)(cur + 8256 + kbp + (wcb + n * 16 + lrow) * 16);
    #pragma unroll
    for (int m = 0; m < 4; ++m)
      #pragma unroll
      for (int n = 0; n < 4; ++n)
        acc[m][n] = __builtin_amdgcn_mfma_f32_16x16x32_bf16(af[m], bfr[n], acc[m][n], 0, 0, 0);
    __syncthreads();                                   // one barrier per K-step
  }
}

// ---------------- Kernel 2: GEMM -> sim (LDS-coalesced, TEMPORAL store) + exp sums ----
__global__ __launch_bounds__(256, 4) void k_gemm(const unsigned short* __restrict__ abf,
                                                 const unsigned short* __restrict__ bbf,
                                                 const float* __restrict__ sq0,
                                                 const float* __restrict__ sq1,
                                                 float* __restrict__ simout,
                                                 float* __restrict__ rowsum,
                                                 float* __restrict__ colsum) {
  __shared__ char lds[33792];                          // dbuf 2x16.5KB; epilogue [64][132]
  int t = threadIdx.x;
  int wid = t >> 6, lane = t & 63;
  int wrb = (wid >> 1) << 6, wcb = (wid & 1) << 6;
  int lrow = lane & 15, kgrp = lane >> 4;

  // bijective XCD-chunked swizzle: 4096 blocks, 8 XCDs, 512 per XCD.
  int wg = blockIdx.x;
  int swz = (wg & 7) * 512 + (wg >> 3);
  int bz = swz >> 10;
  int rem = swz & 1023;
  long tileM = (long)(rem >> 5) * 128;
  long tileS = (long)(rem & 31) * 128;
  const char* aB = (const char*)(abf + ((long)bz * LD + tileM) * CD);
  const char* bB = (const char*)(bbf + ((long)bz * SD + tileS) * CD);

  f32x4 acc[4][4];
  gemm_core(aB, bB, lds, t, acc);

  long gcol0 = (long)bz * SD + tileS + wcb;
  float sq1v[4];
  #pragma unroll
  for (int n = 0; n < 4; ++n) sq1v[n] = sq1[gcol0 + n * 16 + lrow];

  float ce[4] = {0.f, 0.f, 0.f, 0.f};
  float* ltile = (float*)lds;                          // [64][132] padded half-tile

  #pragma unroll
  for (int h = 0; h < 2; ++h) {                        // two 64-row halves
    __syncthreads();                                   // LDS reuse guard
    #pragma unroll
    for (int mm = 0; mm < 2; ++mm) {
      int m = 2 * h + mm;
      #pragma unroll
      for (int i = 0; i < 4; ++i) {
        int lr = m * 16 + kgrp * 4 + i;                // C/D: row=(lane>>4)*4+reg
        long gl = tileM + wrb + lr;
        float s0 = sq0[(long)bz * LD + gl];
        int q = (wid >> 1) * 32 + mm * 16 + kgrp * 4 + i;  // LDS row 0..63
        float rs = 0.f;
        #pragma unroll
        for (int n = 0; n < 4; ++n) {
          float inner = acc[m][n][i];
          float d2 = fmaxf(s0 + sq1v[n] - 2.0f * inner, 0.f);
          float sv = -__builtin_sqrtf(d2) * INV_TC;
          ltile[q * 132 + wcb + n * 16 + lrow] = sv;
          float e = __expf(sv);
          rs += e;
          ce[n] += e;
        }
        #pragma unroll
        for (int d = 1; d < 16; d <<= 1) rs += __shfl_xor(rs, d);
        if (lrow == 0) atomicAdd(&rowsum[(long)bz * LD + gl], rs);
      }
    }
    __syncthreads();
    // cooperative coalesced store: 64 rows x 128 cols, 512B contiguous per row.
    // TEMPORAL store: sim must allocate in L2/L3 so k_softmax's re-read hits cache.
    #pragma unroll
    for (int j = 0; j < 8; ++j) {
      int f = t + 256 * j;                             // 0..2047 float4 slots
      int r = f >> 5;                                  // LDS row 0..63
      int c4 = f & 31;                                 // float4 col 0..31
      long grow = tileM + (r >> 5) * 64 + 32 * h + (r & 31);
      f32x4 v = *(const f32x4*)&ltile[r * 132 + c4 * 4];
      *(f32x4*)(simout + ((long)bz * LD + grow) * SD + tileS + c4 * 4) = v;
    }
  }

  #pragma unroll
  for (int n = 0; n < 4; ++n) {
    float cs = ce[n];
    cs += __shfl_xor(cs, 16);
    cs += __shfl_xor(cs, 32);
    if (kgrp == 0) atomicAdd(&colsum[gcol0 + n * 16 + lrow], cs);
  }
}

// ---------------- Kernel 3: dual softmax + packed row/col argmax (wave-owns-row) ------
// REVERSE read order: k_gemm writes batches/rows in ascending order, so the most
// recently written sim (batch 3, high rows) is L3-resident. Reading in reverse write
// order maximizes L3 hits for the 268MB-vs-256MB capacity stream. Pure reordering —
// outputs bit-identical (packed-max atomics commutative).
__global__ __launch_bounds__(256) void k_softmax(const float* __restrict__ sim,
                                                 const float* __restrict__ rowsum,
                                                 const float* __restrict__ colsum,
                                                 float* __restrict__ conf,
                                                 float* __restrict__ conf0,
                                                 float* __restrict__ conf1,
                                                 unsigned long long* __restrict__ rowpack,
                                                 unsigned long long* __restrict__ colpack) {
  __shared__ unsigned long long rmx[64];
  __shared__ unsigned long long cmx[512];
  int t = threadIdx.x;
  int w = t >> 6, lane = t & 63;
  cmx[t] = 0ull;
  cmx[t + 256] = 0ull;
  __syncthreads();

  int n = NB - 1 - blockIdx.z;                         // reverse batch order
  long rbase = (long)(LD / 64 - 1 - blockIdx.y) * 64;  // reverse row-panel order
  long cbase = (long)blockIdx.x * 512;

  // per-thread fixed column slots: it*256 + lane*4 + q
  float invc[2][4];
  unsigned long long cpk[2][4];
  #pragma unroll
  for (int it = 0; it < 2; ++it) {
    f32x4 cs = *(const f32x4*)(colsum + (long)n * SD + cbase + it * 256 + lane * 4);
    invc[it][0] = 1.0f / cs[0]; invc[it][1] = 1.0f / cs[1];
    invc[it][2] = 1.0f / cs[2]; invc[it][3] = 1.0f / cs[3];
    cpk[it][0] = cpk[it][1] = cpk[it][2] = cpk[it][3] = 0ull;
  }

  #pragma unroll 2
  for (int j = 0; j < 16; ++j) {
    int r = w + j * 4;                                 // wave-uniform row, unique owner
    long gr = rbase + r;
    float invr = 1.0f / rowsum[(long)n * LD + gr];
    long rowoff = ((long)n * LD + gr) * SD + cbase;
    unsigned long long rbest = 0ull;
    #pragma unroll
    for (int it = 0; it < 2; ++it) {
      long idx = rowoff + it * 256 + lane * 4;
      f32x4 sv = *(const f32x4*)(sim + idx);           // TEMPORAL: hit L3-resident sim
      f32x4 cf, c0v, c1v;
      #pragma unroll
      for (int q = 0; q < 4; ++q) {
        float e = __expf(sv[q]);
        float a0 = e * invc[it][q];                    // softmax over L (axis=1)
        float a1 = e * invr;                           // softmax over S (axis=2)
        float c = a0 * a1;
        c0v[q] = a0;
        c1v[q] = a1;
        cf[q] = c;
        unsigned long long pk = ((unsigned long long)__float_as_uint(c) << 32) |
                                (unsigned int)(~(unsigned int)(cbase + it * 256 + lane * 4 + q));
        rbest = pk > rbest ? pk : rbest;
        cpk[it][q] = pk > cpk[it][q] ? pk : cpk[it][q];
      }
      nt_store4(cf, conf + idx);                       // NT: never re-read, don't evict sim
      nt_store4(c0v, conf0 + idx);
      nt_store4(c1v, conf1 + idx);
    }
    #pragma unroll
    for (int d = 1; d < 64; d <<= 1) {                 // one reduce per row (not per tile)
      unsigned long long o = __shfl_xor(rbest, d);
      rbest = o > rbest ? o : rbest;
    }
    if (lane == 0) rmx[r] = rbest;                     // unique writer -> plain store
  }
  #pragma unroll
  for (int it = 0; it < 2; ++it)
    #pragma unroll
    for (int q = 0; q < 4; ++q)
      atomicMax(&cmx[it * 256 + lane * 4 + q], cpk[it][q]);
  __syncthreads();
  if (t < 64) atomicMax(&rowpack[(long)n * LD + rbase + t], rmx[t]);
  atomicMax(&colpack[(long)n * SD + cbase + t], cmx[t]);
  atomicMax(&colpack[(long)n * SD + cbase + 256 + t], cmx[t + 256]);
}

// ---------------- Kernel 4: finalize mutual-NN match outputs --------------------------
__global__ __launch_bounds__(256) void k_final(const unsigned long long* __restrict__ rowpack,
                                               const unsigned long long* __restrict__ colpack,
                                               float* __restrict__ maskv,
                                               float* __restrict__ jids,
                                               float* __restrict__ mconf) {
  long idx = (long)blockIdx.x * 256 + threadIdx.x;
  if (idx >= (long)NB * LD) return;
  int n = (int)(idx / LD);
  unsigned long long rp = rowpack[idx];
  unsigned int cbits = (unsigned int)(rp >> 32);
  float cval = __uint_as_float(cbits);
  unsigned int col = ~(unsigned int)rp;
  bool valid = (cval > THRV) && (col < (unsigned int)SD);
  if (valid) {
    unsigned long long cp = colpack[(long)n * SD + col];
    valid = ((unsigned int)(cp >> 32)) == cbits;       // conf == colmax
  }
  maskv[idx] = valid ? 1.0f : 0.0f;
  jids[idx]  = valid ? (float)col : 0.0f;
  mconf[idx] = valid ? cval : 0.0f;
}

extern "C" void kernel_launch(void* const* d_in, const int* in_sizes, int n_in,
                              void* d_out, int out_size, void* d_ws, size_t ws_size,
                              hipStream_t stream) {
  const float* f0 = (const float*)d_in[0];
  const float* f1 = (const float*)d_in[1];
  float* out = (float*)d_out;
  float* conf  = out;                  // chunk 0
  float* conf0 = out + CHUNK;          // chunk 1
  float* conf1 = out + 2 * CHUNK;      // chunk 2
  float* simo  = out + 3 * CHUNK;      // chunk 3
  float* maskv = out + 4 * CHUNK;      // [N,L]
  float* jids  = maskv + (long)NB * LD;
  float* mconf = jids + (long)NB * LD;

  char* ws = (char*)d_ws;
  unsigned short* abf = (unsigned short*)ws;                         // 8 MiB
  unsigned short* bbf = (unsigned short*)(ws + 8388608);             // 8 MiB
  float* sq0 = (float*)(ws + 16777216);                              // 64 KiB
  float* sq1 = (float*)(ws + 16777216 + 65536);                      // 64 KiB
  char* accums = ws + 16908288;
  float* rowsum = (float*)accums;                                    // 64 KiB
  float* colsum = (float*)(accums + 65536);                          // 64 KiB
  unsigned long long* rowpack = (unsigned long long*)(accums + 131072);   // 128 KiB
  unsigned long long* colpack = (unsigned long long*)(accums + 262144);   // 128 KiB
  (void)hipMemsetAsync(accums, 0, 393216, stream);

  k_prep<<<dim3((NB * (LD + SD)) / 4), dim3(256), 0, stream>>>(f0, f1, abf, bbf, sq0, sq1);
  k_gemm<<<dim3(4096), dim3(256), 0, stream>>>(abf, bbf, sq0, sq1, simo, rowsum, colsum);
  k_softmax<<<dim3(SD / 512, LD / 64, NB), dim3(256), 0, stream>>>(simo, rowsum, colsum,
                                                                   conf, conf0, conf1,
                                                                   rowpack, colpack);
  k_final<<<dim3((NB * LD + 255) / 256), dim3(256), 0, stream>>>(rowpack, colpack,
                                                                 maskv, jids, mconf);
}

// Round 14
// 334.981 us; speedup vs baseline: 1.3241x; 1.0243x over previous
//
#include <hip/hip_runtime.h>
#include <stdint.h>

#define NB 4
#define LD 4096
#define SD 4096
#define CD 256

static constexpr long CHUNK = (long)NB * LD * SD;     // elements per [N,L,S] output
static constexpr float SCALE = 0.0625f;               // 1/sqrt(256)
static constexpr float INV_TC = 1.0f / 25.6f;         // 1/(0.1*256)
static constexpr float THRV = 0.2f;

typedef __attribute__((ext_vector_type(8))) short bf16x8;
typedef __attribute__((ext_vector_type(4))) float f32x4;

__device__ __forceinline__ unsigned short f2bf(float x) {
  unsigned int u = __float_as_uint(x);
  return (unsigned short)((u + 0x7FFFu + ((u >> 16) & 1u)) >> 16);
}

__device__ __forceinline__ void gload_lds16(const void* g, void* l) {
  __builtin_amdgcn_global_load_lds((const __attribute__((address_space(1))) void*)g,
                                   (__attribute__((address_space(3))) void*)l, 16, 0, 0);
}

// NT only for write-once-never-reread streams (conf*): keep them OUT of L2/L3
// so the sim intermediate stays resident between k_gemm and k_softmax.
__device__ __forceinline__ void nt_store4(f32x4 v, float* p) {
  __builtin_nontemporal_store(v, (f32x4*)p);
}

// ---------------- Kernel 1: scale -> bf16 copies + fp32 squared norms (into ws) -------
__global__ __launch_bounds__(256) void k_prep(const float* __restrict__ f0,
                                              const float* __restrict__ f1,
                                              unsigned short* __restrict__ abf,
                                              unsigned short* __restrict__ bbf,
                                              float* __restrict__ sq0,
                                              float* __restrict__ sq1) {
  int wid = threadIdx.x >> 6, lane = threadIdx.x & 63;
  long row = (long)blockIdx.x * 4 + wid;               // over N*(L+S) rows
  const long nl = (long)NB * LD;
  const float* src;
  unsigned short* dst;
  float* sqd;
  if (row < nl) {
    src = f0 + row * CD; dst = abf + row * CD; sqd = sq0 + row;
  } else {
    long r = row - nl;
    src = f1 + r * CD; dst = bbf + r * CD; sqd = sq1 + r;
  }
  f32x4 v = *reinterpret_cast<const f32x4*>(src + lane * 4);
  v *= SCALE;
  ushort4 o;
  o.x = f2bf(v[0]); o.y = f2bf(v[1]); o.z = f2bf(v[2]); o.w = f2bf(v[3]);
  reinterpret_cast<ushort4*>(dst)[lane] = o;
  float s = v[0] * v[0] + v[1] * v[1] + v[2] * v[2] + v[3] * v[3];
  #pragma unroll
  for (int m = 1; m < 64; m <<= 1) s += __shfl_xor(s, m);
  if (lane == 0) *sqd = s;
}

// ---------------- GEMM core: 128x128 tile, BK=32, dbuf, SOUND counted-vmcnt -----------
// Invariant (fix of the R13 race): each wave's counted vmcnt wait comes BEFORE the
// barrier, so crossing the barrier certifies ALL waves' current-buffer loads landed.
// Step kt: issue prefetch(kt+1) [W-A-R safe: prev end-barrier certified all reads of
// that buffer retired] -> vmcnt(4) [my cur loads, issued a full step ago, landed] ->
// s_barrier [everyone's landed] -> ds_read+MFMA -> lgkmcnt(0) -> s_barrier [all reads
// retired before next overwrite]. No vmcnt(0) drain in the steady state.
__device__ __forceinline__ void stage32(const char* aB, const char* bB, char* lbuf,
                                        int kt, int t) {
  #pragma unroll
  for (int i = 0; i < 2; ++i) {
    int s = t + i * 256;                               // slot 0..511
    int ks = s >> 7;                                   // k-plane 0..3 (wave-uniform)
    int r = s & 127;                                   // row 0..127
    long goff = (long)r * (CD * 2) + kt * 64 + ks * 16;
    int loff = ks * 2064 + r * 16;                     // = uniform base + lane*16
    gload_lds16(aB + goff, lbuf + loff);
    gload_lds16(bB + goff, lbuf + 8256 + loff);
  }
}

__device__ __forceinline__ void gemm_core(const char* aB, const char* bB, char* lds,
                                          int t, f32x4 (&acc)[4][4]) {
  int wid = t >> 6, lane = t & 63;
  int wrb = (wid >> 1) << 6;
  int wcb = (wid & 1) << 6;
  int lrow = lane & 15;
  int kgrp = lane >> 4;

  #pragma unroll
  for (int m = 0; m < 4; ++m)
    #pragma unroll
    for (int n = 0; n < 4; ++n)
      acc[m][n] = (f32x4){0.f, 0.f, 0.f, 0.f};

  stage32(aB, bB, lds, 0, t);                          // prologue: buf0's 4 loads

  #pragma unroll
  for (int kt = 0; kt < 8; ++kt) {
    char* cur = lds + (kt & 1) * 16512;
    if (kt < 7) {
      // prefetch next buffer: its previous readers all retired (prev end-barrier)
      stage32(aB, bB, lds + ((kt + 1) & 1) * 16512, kt + 1, t);
      __builtin_amdgcn_sched_barrier(0);
      asm volatile("s_waitcnt vmcnt(4)" ::: "memory"); // MY cur loads landed
    } else {
      __builtin_amdgcn_sched_barrier(0);
      asm volatile("s_waitcnt vmcnt(0)" ::: "memory"); // last buffer: all landed
    }
    __builtin_amdgcn_s_barrier();                      // EVERYONE's cur loads landed
    __builtin_amdgcn_sched_barrier(0);
    int kbp = kgrp * 2064;                             // this lane's k-plane
    bf16x8 af[4], bfr[4];
    #pragma unroll
    for (int m = 0; m < 4; ++m)
      af[m] = *(const bf16x8*)(cur + kbp + (wrb + m * 16 + lrow) * 16);
    #pragma unroll
    for (int n = 0; n < 4; ++n)
      bfr[n] = *(const bf16x8*)(cur + 8256 + kbp + (wcb + n * 16 + lrow) * 16);
    #pragma unroll
    for (int m = 0; m < 4; ++m)
      #pragma unroll
      for (int n = 0; n < 4; ++n)
        acc[m][n] = __builtin_amdgcn_mfma_f32_16x16x32_bf16(af[m], bfr[n], acc[m][n], 0, 0, 0);
    __builtin_amdgcn_sched_barrier(0);
    asm volatile("s_waitcnt lgkmcnt(0)" ::: "memory"); // my ds_reads retired
    __builtin_amdgcn_s_barrier();                      // all reads retired (W-A-R)
    __builtin_amdgcn_sched_barrier(0);
  }
}

// ---------------- Kernel 2: GEMM -> sim (LDS-coalesced, TEMPORAL store) + exp sums ----
__global__ __launch_bounds__(256, 4) void k_gemm(const unsigned short* __restrict__ abf,
                                                 const unsigned short* __restrict__ bbf,
                                                 const float* __restrict__ sq0,
                                                 const float* __restrict__ sq1,
                                                 float* __restrict__ simout,
                                                 float* __restrict__ rowsum,
                                                 float* __restrict__ colsum) {
  __shared__ char lds[33792];                          // dbuf 2x16.5KB; epilogue [64][132]
  int t = threadIdx.x;
  int wid = t >> 6, lane = t & 63;
  int wrb = (wid >> 1) << 6, wcb = (wid & 1) << 6;
  int lrow = lane & 15, kgrp = lane >> 4;

  // bijective XCD-chunked swizzle: 4096 blocks, 8 XCDs, 512 per XCD.
  int wg = blockIdx.x;
  int swz = (wg & 7) * 512 + (wg >> 3);
  int bz = swz >> 10;
  int rem = swz & 1023;
  long tileM = (long)(rem >> 5) * 128;
  long tileS = (long)(rem & 31) * 128;
  const char* aB = (const char*)(abf + ((long)bz * LD + tileM) * CD);
  const char* bB = (const char*)(bbf + ((long)bz * SD + tileS) * CD);

  f32x4 acc[4][4];
  gemm_core(aB, bB, lds, t, acc);

  long gcol0 = (long)bz * SD + tileS + wcb;
  float sq1v[4];
  #pragma unroll
  for (int n = 0; n < 4; ++n) sq1v[n] = sq1[gcol0 + n * 16 + lrow];

  float ce[4] = {0.f, 0.f, 0.f, 0.f};
  float* ltile = (float*)lds;                          // [64][132] padded half-tile

  #pragma unroll
  for (int h = 0; h < 2; ++h) {                        // two 64-row halves
    __syncthreads();                                   // LDS reuse guard (full drain)
    #pragma unroll
    for (int mm = 0; mm < 2; ++mm) {
      int m = 2 * h + mm;
      #pragma unroll
      for (int i = 0; i < 4; ++i) {
        int lr = m * 16 + kgrp * 4 + i;                // C/D: row=(lane>>4)*4+reg
        long gl = tileM + wrb + lr;
        float s0 = sq0[(long)bz * LD + gl];
        int q = (wid >> 1) * 32 + mm * 16 + kgrp * 4 + i;  // LDS row 0..63
        float rs = 0.f;
        #pragma unroll
        for (int n = 0; n < 4; ++n) {
          float inner = acc[m][n][i];
          float d2 = fmaxf(s0 + sq1v[n] - 2.0f * inner, 0.f);
          float sv = -__builtin_sqrtf(d2) * INV_TC;
          ltile[q * 132 + wcb + n * 16 + lrow] = sv;
          float e = __expf(sv);
          rs += e;
          ce[n] += e;
        }
        #pragma unroll
        for (int d = 1; d < 16; d <<= 1) rs += __shfl_xor(rs, d);
        if (lrow == 0) atomicAdd(&rowsum[(long)bz * LD + gl], rs);
      }
    }
    __syncthreads();
    // cooperative coalesced store: 64 rows x 128 cols, 512B contiguous per row.
    // TEMPORAL store: sim must allocate in L2/L3 so k_softmax's re-read hits cache.
    #pragma unroll
    for (int j = 0; j < 8; ++j) {
      int f = t + 256 * j;                             // 0..2047 float4 slots
      int r = f >> 5;                                  // LDS row 0..63
      int c4 = f & 31;                                 // float4 col 0..31
      long grow = tileM + (r >> 5) * 64 + 32 * h + (r & 31);
      f32x4 v = *(const f32x4*)&ltile[r * 132 + c4 * 4];
      *(f32x4*)(simout + ((long)bz * LD + grow) * SD + tileS + c4 * 4) = v;
    }
  }

  #pragma unroll
  for (int n = 0; n < 4; ++n) {
    float cs = ce[n];
    cs += __shfl_xor(cs, 16);
    cs += __shfl_xor(cs, 32);
    if (kgrp == 0) atomicAdd(&colsum[gcol0 + n * 16 + lrow], cs);
  }
}

// ---------------- Kernel 3: dual softmax + packed row/col argmax (wave-owns-row) ------
// REVERSE read order: most recently written sim (batch 3, high rows) is L3-resident;
// reading in reverse write order maximizes hits for the 268MB-vs-256MB stream.
__global__ __launch_bounds__(256) void k_softmax(const float* __restrict__ sim,
                                                 const float* __restrict__ rowsum,
                                                 const float* __restrict__ colsum,
                                                 float* __restrict__ conf,
                                                 float* __restrict__ conf0,
                                                 float* __restrict__ conf1,
                                                 unsigned long long* __restrict__ rowpack,
                                                 unsigned long long* __restrict__ colpack) {
  __shared__ unsigned long long rmx[64];
  __shared__ unsigned long long cmx[512];
  int t = threadIdx.x;
  int w = t >> 6, lane = t & 63;
  cmx[t] = 0ull;
  cmx[t + 256] = 0ull;
  __syncthreads();

  int n = NB - 1 - blockIdx.z;                         // reverse batch order
  long rbase = (long)(LD / 64 - 1 - blockIdx.y) * 64;  // reverse row-panel order
  long cbase = (long)blockIdx.x * 512;

  // per-thread fixed column slots: it*256 + lane*4 + q
  float invc[2][4];
  unsigned long long cpk[2][4];
  #pragma unroll
  for (int it = 0; it < 2; ++it) {
    f32x4 cs = *(const f32x4*)(colsum + (long)n * SD + cbase + it * 256 + lane * 4);
    invc[it][0] = 1.0f / cs[0]; invc[it][1] = 1.0f / cs[1];
    invc[it][2] = 1.0f / cs[2]; invc[it][3] = 1.0f / cs[3];
    cpk[it][0] = cpk[it][1] = cpk[it][2] = cpk[it][3] = 0ull;
  }

  #pragma unroll 2
  for (int j = 0; j < 16; ++j) {
    int r = w + j * 4;                                 // wave-uniform row, unique owner
    long gr = rbase + r;
    float invr = 1.0f / rowsum[(long)n * LD + gr];
    long rowoff = ((long)n * LD + gr) * SD + cbase;
    unsigned long long rbest = 0ull;
    #pragma unroll
    for (int it = 0; it < 2; ++it) {
      long idx = rowoff + it * 256 + lane * 4;
      f32x4 sv = *(const f32x4*)(sim + idx);           // TEMPORAL: hit L3-resident sim
      f32x4 cf, c0v, c1v;
      #pragma unroll
      for (int q = 0; q < 4; ++q) {
        float e = __expf(sv[q]);
        float a0 = e * invc[it][q];                    // softmax over L (axis=1)
        float a1 = e * invr;                           // softmax over S (axis=2)
        float c = a0 * a1;
        c0v[q] = a0;
        c1v[q] = a1;
        cf[q] = c;
        unsigned long long pk = ((unsigned long long)__float_as_uint(c) << 32) |
                                (unsigned int)(~(unsigned int)(cbase + it * 256 + lane * 4 + q));
        rbest = pk > rbest ? pk : rbest;
        cpk[it][q] = pk > cpk[it][q] ? pk : cpk[it][q];
      }
      nt_store4(cf, conf + idx);                       // NT: never re-read, don't evict sim
      nt_store4(c0v, conf0 + idx);
      nt_store4(c1v, conf1 + idx);
    }
    #pragma unroll
    for (int d = 1; d < 64; d <<= 1) {                 // one reduce per row (not per tile)
      unsigned long long o = __shfl_xor(rbest, d);
      rbest = o > rbest ? o : rbest;
    }
    if (lane == 0) rmx[r] = rbest;                     // unique writer -> plain store
  }
  #pragma unroll
  for (int it = 0; it < 2; ++it)
    #pragma unroll
    for (int q = 0; q < 4; ++q)
      atomicMax(&cmx[it * 256 + lane * 4 + q], cpk[it][q]);
  __syncthreads();
  if (t < 64) atomicMax(&rowpack[(long)n * LD + rbase + t], rmx[t]);
  atomicMax(&colpack[(long)n * SD + cbase + t], cmx[t]);
  atomicMax(&colpack[(long)n * SD + cbase + 256 + t], cmx[t + 256]);
}

// ---------------- Kernel 4: finalize mutual-NN match outputs --------------------------
__global__ __launch_bounds__(256) void k_final(const unsigned long long* __restrict__ rowpack,
                                               const unsigned long long* __restrict__ colpack,
                                               float* __restrict__ maskv,
                                               float* __restrict__ jids,
                                               float* __restrict__ mconf) {
  long idx = (long)blockIdx.x * 256 + threadIdx.x;
  if (idx >= (long)NB * LD) return;
  int n = (int)(idx / LD);
  unsigned long long rp = rowpack[idx];
  unsigned int cbits = (unsigned int)(rp >> 32);
  float cval = __uint_as_float(cbits);
  unsigned int col = ~(unsigned int)rp;
  bool valid = (cval > THRV) && (col < (unsigned int)SD);
  if (valid) {
    unsigned long long cp = colpack[(long)n * SD + col];
    valid = ((unsigned int)(cp >> 32)) == cbits;       // conf == colmax
  }
  maskv[idx] = valid ? 1.0f : 0.0f;
  jids[idx]  = valid ? (float)col : 0.0f;
  mconf[idx] = valid ? cval : 0.0f;
}

extern "C" void kernel_launch(void* const* d_in, const int* in_sizes, int n_in,
                              void* d_out, int out_size, void* d_ws, size_t ws_size,
                              hipStream_t stream) {
  const float* f0 = (const float*)d_in[0];
  const float* f1 = (const float*)d_in[1];
  float* out = (float*)d_out;
  float* conf  = out;                  // chunk 0
  float* conf0 = out + CHUNK;          // chunk 1
  float* conf1 = out + 2 * CHUNK;      // chunk 2
  float* simo  = out + 3 * CHUNK;      // chunk 3
  float* maskv = out + 4 * CHUNK;      // [N,L]
  float* jids  = maskv + (long)NB * LD;
  float* mconf = jids + (long)NB * LD;

  char* ws = (char*)d_ws;
  unsigned short* abf = (unsigned short*)ws;                         // 8 MiB
  unsigned short* bbf = (unsigned short*)(ws + 8388608);             // 8 MiB
  float* sq0 = (float*)(ws + 16777216);                              // 64 KiB
  float* sq1 = (float*)(ws + 16777216 + 65536);                      // 64 KiB
  char* accums = ws + 16908288;
  float* rowsum = (float*)accums;                                    // 64 KiB
  float* colsum = (float*)(accums + 65536);                          // 64 KiB
  unsigned long long* rowpack = (unsigned long long*)(accums + 131072);   // 128 KiB
  unsigned long long* colpack = (unsigned long long*)(accums + 262144);   // 128 KiB
  (void)hipMemsetAsync(accums, 0, 393216, stream);

  k_prep<<<dim3((NB * (LD + SD)) / 4), dim3(256), 0, stream>>>(f0, f1, abf, bbf, sq0, sq1);
  k_gemm<<<dim3(4096), dim3(256), 0, stream>>>(abf, bbf, sq0, sq1, simo, rowsum, colsum);
  k_softmax<<<dim3(SD / 512, LD / 64, NB), dim3(256), 0, stream>>>(simo, rowsum, colsum,
                                                                   conf, conf0, conf1,
                                                                   rowpack, colpack);
  k_final<<<dim3((NB * LD + 255) / 256), dim3(256), 0, stream>>>(rowpack, colpack,
                                                                 maskv, jids, mconf);
}